// Round 1
// baseline (1849.108 us; speedup 1.0000x reference)
//
#include <hip/hip_runtime.h>

typedef __bf16 bf16;
typedef __attribute__((ext_vector_type(4))) float floatx4;
typedef __attribute__((ext_vector_type(8))) bf16 bf16x8;
typedef __attribute__((ext_vector_type(4))) bf16 bf16x4;

typedef const __attribute__((address_space(1))) void gconst_t;
typedef __attribute__((address_space(3))) void lds_t;

__device__ __forceinline__ void load_lds16(const void* g, void* l) {
  __builtin_amdgcn_global_load_lds((gconst_t*)g, (lds_t*)l, 16, 0, 0);
}

__device__ __forceinline__ float sigm(float x) { return 1.f / (1.f + __expf(-x)); }
__device__ __forceinline__ float tanh_f(float x) { return 2.f / (1.f + __expf(-2.f * x)) - 1.f; }

// ---------------------------------------------------------------------------
// fp32 -> bf16 convert (vectorized x4)
// ---------------------------------------------------------------------------
__global__ void k_cvt(const float* __restrict__ in, bf16* __restrict__ out, int n4) {
  int i = blockIdx.x * 256 + threadIdx.x;
  if (i < n4) {
    float4 v = ((const float4*)in)[i];
    bf16x4 u = { (bf16)v.x, (bf16)v.y, (bf16)v.z, (bf16)v.w };
    ((bf16x4*)out)[i] = u;
  }
}

__global__ void k_bias_sum(const float* __restrict__ a, const float* __restrict__ b,
                           float* __restrict__ o, int n) {
  int i = blockIdx.x * 256 + threadIdx.x;
  if (i < n) o[i] = a[i] + b[i];
}

// ---------------------------------------------------------------------------
// linear (32x2048 @ 2048x512^T) + batchnorm over batch dim -> xs row t=0 (bf16)
// one block per output feature e; BN stats over the 32 batch values in-block
// ---------------------------------------------------------------------------
__global__ __launch_bounds__(256) void k_linbn(
    const float* __restrict__ img, const float* __restrict__ W,
    const float* __restrict__ lb, const float* __restrict__ gamma,
    const float* __restrict__ beta, bf16* __restrict__ xs)
{
  const int e = blockIdx.x;                 // 0..511
  const int wave = threadIdx.x >> 6, lane = threadIdx.x & 63;
  __shared__ float sums[32];
  const float* wrow = W + (size_t)e * 2048;
  for (int b = wave; b < 32; b += 4) {
    const float* irow = img + (size_t)b * 2048;
    float s = 0.f;
#pragma unroll
    for (int j = 0; j < 8; ++j) {
      const int k = j * 256 + lane * 4;
      float4 a = *(const float4*)(irow + k);
      float4 w = *(const float4*)(wrow + k);
      s += a.x * w.x + a.y * w.y + a.z * w.z + a.w * w.w;
    }
#pragma unroll
    for (int off = 32; off > 0; off >>= 1) s += __shfl_down(s, off);
    if (lane == 0) sums[b] = s + lb[e];
  }
  __syncthreads();
  if (threadIdx.x < 32) {
    const float x = sums[threadIdx.x];
    float m = x, m2 = x * x;
#pragma unroll
    for (int mask = 16; mask > 0; mask >>= 1) {
      m  += __shfl_xor(m, mask);
      m2 += __shfl_xor(m2, mask);
    }
    m *= (1.f / 32.f); m2 *= (1.f / 32.f);
    const float var = m2 - m * m;
    const float xn = gamma[e] * (x - m) * rsqrtf(var + 1e-5f) + beta[e];
    xs[(size_t)threadIdx.x * 64 * 512 + e] = (bf16)xn;  // row r = b*64 + 0
  }
}

// ---------------------------------------------------------------------------
// embedding gather -> xs rows t=1..63 (bf16). block = (b, t-1), 128 threads
// ---------------------------------------------------------------------------
__global__ void k_embed(const int* __restrict__ cap, const float* __restrict__ emb,
                        bf16* __restrict__ xs)
{
  const int blk = blockIdx.x;               // 0..2015
  const int b = blk / 63, j = blk % 63;     // t = j+1
  const int tok = cap[b * 64 + j];
  const float* src = emb + (size_t)tok * 512;
  bf16* dst = xs + ((size_t)b * 64 + j + 1) * 512;
  float4 v = ((const float4*)src)[threadIdx.x];
  bf16x4 u = { (bf16)v.x, (bf16)v.y, (bf16)v.z, (bf16)v.w };
  *(bf16x4*)(dst + threadIdx.x * 4) = u;
}

// ---------------------------------------------------------------------------
// GEMM: C[M,N] = A[M,K](bf16) @ Bt[N,K](fp32, converted during staging)^T + bias
// M = 2048 implicit by grid.x*128; exact tiles only. m97 structure:
// 128x128 tile, BK=32, 4 waves in 2x2, 4x4 16x16x32 MFMA tiles per wave.
// ---------------------------------------------------------------------------
__global__ __launch_bounds__(256) void k_gemm(
    const bf16* __restrict__ A, const float* __restrict__ Bt,
    const float* __restrict__ bias, float* __restrict__ C,
    int K, int N)
{
  __shared__ bf16 lA[128 * 32];
  __shared__ bf16 lB[128 * 32];
  const int tid = threadIdx.x;
  const int lane = tid & 63;
  const int wm = ((tid >> 6) >> 1) * 64;
  const int wn = ((tid >> 6) & 1) * 64;
  const size_t row0 = (size_t)blockIdx.x * 128;
  const size_t col0 = (size_t)blockIdx.y * 128;
  floatx4 acc[4][4] = {};
  const bf16*  aSrc = A  + (row0 + (tid >> 2)) * (size_t)K + (tid & 3) * 8;
  const float* bSrc = Bt + (col0 + (tid >> 3)) * (size_t)K + (tid & 7) * 4;
  char* lAb = (char*)&lA[0];

  for (int k0 = 0; k0 < K; k0 += 32) {
    __syncthreads();
#pragma unroll
    for (int s = 0; s < 2; ++s)   // A tile: 128x32 bf16 via lds-DMA, 2 shots
      load_lds16(aSrc + (size_t)s * 64 * K + k0, lAb + s * 4096 + tid * 16);
#pragma unroll
    for (int s = 0; s < 4; ++s) { // B tile: 128x32 fp32 -> bf16, 4 shots
      float4 v = *(const float4*)(bSrc + (size_t)s * 32 * K + k0);
      bf16x4 u = { (bf16)v.x, (bf16)v.y, (bf16)v.z, (bf16)v.w };
      *(bf16x4*)&lB[(s * 32 + (tid >> 3)) * 32 + (tid & 7) * 4] = u;
    }
    __syncthreads();
    bf16x8 af[4], bfv[4];
#pragma unroll
    for (int i = 0; i < 4; ++i)
      af[i] = *(const bf16x8*)&lA[(wm + i * 16 + (lane & 15)) * 32 + (lane >> 4) * 8];
#pragma unroll
    for (int j = 0; j < 4; ++j)
      bfv[j] = *(const bf16x8*)&lB[(wn + j * 16 + (lane & 15)) * 32 + (lane >> 4) * 8];
#pragma unroll
    for (int i = 0; i < 4; ++i)
#pragma unroll
      for (int j = 0; j < 4; ++j)
        acc[i][j] = __builtin_amdgcn_mfma_f32_16x16x32_bf16(af[i], bfv[j], acc[i][j], 0, 0, 0);
  }
#pragma unroll
  for (int i = 0; i < 4; ++i)
#pragma unroll
    for (int j = 0; j < 4; ++j)
#pragma unroll
      for (int r = 0; r < 4; ++r) {
        const size_t row = row0 + wm + i * 16 + (lane >> 4) * 4 + r;
        const size_t col = col0 + wn + j * 16 + (lane & 15);
        C[row * (size_t)N + col] = acc[i][j][r] + bias[col];
      }
}

// ---------------------------------------------------------------------------
// One LSTM scan step: g = pre[:,t,:] + h_{t-1} @ Whh^T; gates; write h_t, c_t.
// grid 64 blocks (16 hidden cols each), wave q = gate q. h staged in LDS in
// 256-wide k-slabs with +8 bf16 row padding (2-way banks instead of 16-way).
// ---------------------------------------------------------------------------
__global__ __launch_bounds__(256) void k_lstm_step(
    bf16* __restrict__ hs, const float* __restrict__ pre,
    const bf16* __restrict__ Whh, float* __restrict__ cst, int t)
{
  __shared__ bf16 lh[32][264];       // 32 x 256 bf16 slab, rows padded +8
  __shared__ float lg[4][32][16];    // gate exchange
  const int tid = threadIdx.x;
  const int lane = tid & 63;
  const int q = tid >> 6;            // wave index == gate index
  const int n0 = blockIdx.x * 16;
  floatx4 acc[2] = {};

  if (t > 0) {
    const bf16* hprev = hs + (size_t)(t - 1) * 1024;   // + b*64*1024 per row
#pragma unroll 1
    for (int slab = 0; slab < 4; ++slab) {
      __syncthreads();
#pragma unroll
      for (int it = 0; it < 4; ++it) { // stage 32x256 bf16 slab of h_{t-1}
        const int f = it * 256 + tid;
        const int row = f >> 5, c8 = (f & 31) * 8;
        float4 v = *(const float4*)(hprev + (size_t)row * 65536 + slab * 256 + c8);
        *(float4*)&lh[row][c8] = v;
      }
      __syncthreads();
      const bf16* wrow = Whh + ((size_t)q * 1024 + n0 + (lane & 15)) * 1024
                             + slab * 256 + (lane >> 4) * 8;
#pragma unroll
      for (int kk = 0; kk < 8; ++kk) {
        bf16x8 bv = *(const bf16x8*)(wrow + kk * 32);
        bf16x8 a0 = *(const bf16x8*)&lh[(lane & 15)][kk * 32 + (lane >> 4) * 8];
        bf16x8 a1 = *(const bf16x8*)&lh[16 + (lane & 15)][kk * 32 + (lane >> 4) * 8];
        acc[0] = __builtin_amdgcn_mfma_f32_16x16x32_bf16(a0, bv, acc[0], 0, 0, 0);
        acc[1] = __builtin_amdgcn_mfma_f32_16x16x32_bf16(a1, bv, acc[1], 0, 0, 0);
      }
    }
  }
#pragma unroll
  for (int i = 0; i < 2; ++i)
#pragma unroll
    for (int r = 0; r < 4; ++r)
      lg[q][i * 16 + (lane >> 4) * 4 + r][lane & 15] = acc[i][r];
  __syncthreads();
#pragma unroll
  for (int p = 0; p < 2; ++p) {
    const int idx = p * 256 + tid;
    const int b = idx >> 4, nl = idx & 15;
    const int n = n0 + nl;
    const float* pb = pre + ((size_t)b * 64 + t) * 4096 + n;
    const float gi = lg[0][b][nl] + pb[0];
    const float gf = lg[1][b][nl] + pb[1024];
    const float gg = lg[2][b][nl] + pb[2048];
    const float go = lg[3][b][nl] + pb[3072];
    const float iv = sigm(gi), fv = sigm(gf), gv = tanh_f(gg), ov = sigm(go);
    const float cp = (t > 0) ? cst[b * 1024 + n] : 0.f;
    const float cn = fv * cp + iv * gv;
    cst[b * 1024 + n] = cn;
    hs[((size_t)b * 64 + t) * 1024 + n] = (bf16)(ov * tanh_f(cn));
  }
}

// ---------------------------------------------------------------------------
extern "C" void kernel_launch(void* const* d_in, const int* in_sizes, int n_in,
                              void* d_out, int out_size, void* d_ws, size_t ws_size,
                              hipStream_t stream)
{
  const float* image = (const float*)d_in[0];
  const int*   caps  = (const int*)d_in[1];
  const float* linW  = (const float*)d_in[2];
  const float* linb  = (const float*)d_in[3];
  const float* gamma = (const float*)d_in[4];
  const float* beta  = (const float*)d_in[5];
  const float* emb   = (const float*)d_in[6];
  const float* Wih0  = (const float*)d_in[7];
  const float* Whh0  = (const float*)d_in[8];
  const float* bih0  = (const float*)d_in[9];
  const float* bhh0  = (const float*)d_in[10];
  const float* Wih1  = (const float*)d_in[11];
  const float* Whh1  = (const float*)d_in[12];
  const float* bih1  = (const float*)d_in[13];
  const float* bhh1  = (const float*)d_in[14];
  const float* fcW   = (const float*)d_in[15];
  const float* fcb   = (const float*)d_in[16];
  float* out = (float*)d_out;

  char* ws = (char*)d_ws;
  size_t off = 0;
  auto alloc = [&](size_t bytes) {
    char* p = ws + off;
    off += (bytes + 255) & ~(size_t)255;
    return p;
  };
  bf16*  whh0b = (bf16*)alloc(4096ull * 1024 * 2);
  bf16*  whh1b = (bf16*)alloc(4096ull * 1024 * 2);
  bf16*  xsb   = (bf16*)alloc(2048ull * 512 * 2);
  bf16*  hs0b  = (bf16*)alloc(2048ull * 1024 * 2);
  bf16*  hs1b  = (bf16*)alloc(2048ull * 1024 * 2);
  float* pre   = (float*)alloc(2048ull * 4096 * 4);
  float* bsum0 = (float*)alloc(4096 * 4);
  float* bsum1 = (float*)alloc(4096 * 4);
  float* cst   = (float*)alloc(32 * 1024 * 4);

  k_cvt<<<4096, 256, 0, stream>>>(Whh0, whh0b, 4096 * 1024 / 4);
  k_cvt<<<4096, 256, 0, stream>>>(Whh1, whh1b, 4096 * 1024 / 4);
  k_bias_sum<<<16, 256, 0, stream>>>(bih0, bhh0, bsum0, 4096);
  k_bias_sum<<<16, 256, 0, stream>>>(bih1, bhh1, bsum1, 4096);
  k_linbn<<<512, 256, 0, stream>>>(image, linW, linb, gamma, beta, xsb);
  k_embed<<<2016, 128, 0, stream>>>(caps, emb, xsb);

  // layer 0
  k_gemm<<<dim3(16, 32), 256, 0, stream>>>(xsb, Wih0, bsum0, pre, 512, 4096);
  for (int t = 0; t < 64; ++t)
    k_lstm_step<<<64, 256, 0, stream>>>(hs0b, pre, whh0b, cst, t);
  // layer 1
  k_gemm<<<dim3(16, 32), 256, 0, stream>>>(hs0b, Wih1, bsum1, pre, 1024, 4096);
  for (int t = 0; t < 64; ++t)
    k_lstm_step<<<64, 256, 0, stream>>>(hs1b, pre, whh1b, cst, t);
  // vocab projection
  k_gemm<<<dim3(16, 250), 256, 0, stream>>>(hs1b, fcW, fcb, out, 1024, 32000);

  (void)in_sizes; (void)n_in; (void)out_size; (void)ws_size;
}